// Round 12
// baseline (101.272 us; speedup 1.0000x reference)
//
#include <hip/hip_runtime.h>
#include <hip/hip_bf16.h>
#include <math.h>

#define VOCAB 2048
#define EMB 256
#define MAXLEN 8
#define NBATCH 16
#define LAT 16
#define NBLK 128
#define AGENT __HIP_MEMORY_SCOPE_AGENT

typedef unsigned short u16;
typedef unsigned int u32;
using bf16x8 = __attribute__((ext_vector_type(8))) short;
using f32x4  = __attribute__((ext_vector_type(4))) float;

__device__ __forceinline__ int token_of(float v) {
    float u = v * 2048.0f;
    if (!(u >= 0.0f) || u > 2048.0f) return 0;   // v<0, v>1, or NaN
    int k = (int)ceilf(u) - 1;
    return k < 0 ? 0 : k;
}

__device__ __forceinline__ float sigmoidf_(float x) { return 1.0f / (1.0f + expf(-x)); }

__device__ __forceinline__ u16 to_bf16(float x) {
    __hip_bfloat16 hb = __float2bfloat16(x);   // RTNE
    return *reinterpret_cast<u16*>(&hb);
}

// Cross-block (cross-XCD) accessors: sc0/sc1 bits bypass the non-coherent
// L1/L2 so data moves via the coherent point (L3). Stores ordered by vmcnt(0).
__device__ __forceinline__ void st_ag_f32(float* p, float v) {
    __hip_atomic_store(p, v, __ATOMIC_RELAXED, AGENT);
}
__device__ __forceinline__ float ld_ag_f32(const float* p) {
    return __hip_atomic_load(const_cast<float*>(p), __ATOMIC_RELAXED, AGENT);
}
__device__ __forceinline__ void st_ag_u32(u32* p, u32 v) {
    __hip_atomic_store(p, v, __ATOMIC_RELAXED, AGENT);
}
// Batched pipelined L2-bypass load: 64 B per thread, single vmcnt drain.
__device__ __forceinline__ void stage4(const u16* src, uint4& r0, uint4& r1,
                                       uint4& r2, uint4& r3) {
    asm volatile(
        "global_load_dwordx4 %0, %4, off sc0 sc1\n\t"
        "global_load_dwordx4 %1, %4, off offset:16 sc0 sc1\n\t"
        "global_load_dwordx4 %2, %4, off offset:32 sc0 sc1\n\t"
        "global_load_dwordx4 %3, %4, off offset:48 sc0 sc1\n\t"
        "s_waitcnt vmcnt(0)"
        : "=&v"(r0), "=&v"(r1), "=&v"(r2), "=&v"(r3)
        : "v"(src)
        : "memory");
}

// Slot-per-block barrier: no atomic hot-spot; 128 parallel polls.
// All 128 blocks co-resident (128 blocks <= 256 CUs).
__device__ __forceinline__ void gridbar(int* slots, int phase) {
    asm volatile("s_waitcnt vmcnt(0)" ::: "memory");
    __syncthreads();
    if (threadIdx.x == 0)
        __hip_atomic_store(&slots[phase * NBLK + (int)blockIdx.x], 1,
                           __ATOMIC_RELAXED, AGENT);
    if (threadIdx.x < NBLK)
        while (__hip_atomic_load(&slots[phase * NBLK + (int)threadIdx.x],
                                 __ATOMIC_RELAXED, AGENT) != 1)
            __builtin_amdgcn_s_sleep(1);
    __syncthreads();
}

// ---- K1: Wr -> BW pack. Fragment (l,i) = bf16(W[(k0*32+8*(l>>4)+i)*8192 +
// ntile*16 + (l&15)]); storage block-contiguous: st = (ntile&127)*4 + ntile>>7.
__global__ __launch_bounds__(256) void k_pack(const float* __restrict__ Wr,
                                              u16* __restrict__ BW) {
    int gidx = blockIdx.x * 256 + threadIdx.x;
    int l = gidx & 63;
    int k0 = (gidx >> 6) & 63;
    int ntile = gidx >> 12;
    const float* s = Wr + (size_t)(k0 * 32 + 8 * (l >> 4)) * 8192 + ntile * 16 + (l & 15);
    u16 o[8];
    #pragma unroll
    for (int i = 0; i < 8; ++i) o[i] = to_bf16(s[(size_t)i * 8192]);
    int st = (ntile & 127) * 4 + (ntile >> 7);
    *(uint4*)(BW + ((size_t)(st * 64 + k0) * 64 + l) * 8) = *(uint4*)o;
}

// ---- K2: Wk -> BWk pack (0..1023) + XA pack (1024..1039) + slot zero (1040..1043).
__global__ __launch_bounds__(256) void k_prep(
        const float* __restrict__ Wk, u16* __restrict__ BWk,
        const float* __restrict__ ip, const float* __restrict__ E,
        u16* __restrict__ XA, int* __restrict__ slots) {
    int bx = blockIdx.x;
    int tid = threadIdx.x;
    if (bx < 1024) {
        int gidx = bx * 256 + tid;
        int l = gidx & 63;
        int k0 = (gidx >> 6) & 7;
        int ntile = gidx >> 9;
        const float* s = Wk + (size_t)(k0 * 32 + 8 * (l >> 4)) * 8192 + ntile * 16 + (l & 15);
        u16 o[8];
        #pragma unroll
        for (int i = 0; i < 8; ++i) o[i] = to_bf16(s[(size_t)i * 8192]);
        int st = (ntile & 127) * 4 + (ntile >> 7);
        *(uint4*)(BWk + ((size_t)(st * 8 + k0) * 64 + l) * 8) = *(uint4*)o;
    } else if (bx < 1040) {
        int gidx = (bx - 1024) * 256 + tid;   // 0..4095
        int l = gidx & 63;
        int k0 = (gidx >> 6) & 7;
        int t = gidx >> 9;
        int b = l & 15;
        int tok = token_of(ip[b * LAT + t]);
        const float* s = E + (size_t)tok * EMB + k0 * 32 + 8 * (l >> 4);
        u16 o[8];
        #pragma unroll
        for (int i = 0; i < 8; ++i) o[i] = to_bf16(s[i]);
        *(uint4*)(XA + (size_t)gidx * 8) = *(uint4*)o;
    } else {
        int idx = (bx - 1040) * 256 + tid;    // 0..1023 = 8 phases x 128 slots
        slots[idx] = 0;
    }
}

// ---- K3: persistent sequence. 128 blocks x 1024 thr (16 waves).
// Block bid owns u-tile [bid*16, bid*16+16) for all 4 gates (st = bid*4+g).
// Phases: XZ(all t -> LDS)+step0 | bar0 | 7x(stage hA -> LDS; GEMM+update | bar) | softmax.
__global__ __launch_bounds__(1024) void k_seq(
        const u16* __restrict__ BW, const u16* __restrict__ BWk,
        const u16* __restrict__ XA, const float* __restrict__ bv,
        const float* __restrict__ ip, u16* __restrict__ hA0,
        u16* __restrict__ hA1, float* __restrict__ H,
        float* __restrict__ out, int* __restrict__ slots) {
    int tid = threadIdx.x;
    int bid = blockIdx.x;        // 0..127
    int w = tid >> 6;            // 0..15
    int l = tid & 63;

    __shared__ float xzsh[8][4][256];        // 32 KB
    __shared__ float zsh[16][256];           // 16 KB
    __shared__ __align__(16) u16 hAsh[32768]; // 64 KB: staged hA fragments
    __shared__ float redm[16], reds[16];

    float h_reg = 0.0f, c_reg = 0.0f;   // persistent state (tid<256)
    int bb = tid >> 4;                  // batch (valid tid<256)
    int ul = tid & 15;
    int myu = bid * 16 + ul;            // owned u (valid tid<256)

    // ---- Phase XZ: wave (g = w>>2, tp = w&3) computes xz for t = 2tp, 2tp+1 ----
    {
        int g = w >> 2, tp = w & 3;
        int st = bid * 4 + g;
        const bf16x8* bp = (const bf16x8*)(BWk + ((size_t)(st * 8) * 64 + l) * 8);
        bf16x8 bw[8];
        #pragma unroll
        for (int s = 0; s < 8; ++s) bw[s] = bp[s * 64];
        float bias = bv[g * 2048 + bid * 16 + (l & 15)];
        #pragma unroll
        for (int q = 0; q < 2; ++q) {
            int t = tp * 2 + q;
            const bf16x8* ap = (const bf16x8*)(XA + ((size_t)(t * 8) * 64 + l) * 8);
            bf16x8 av[8];
            #pragma unroll
            for (int s = 0; s < 8; ++s) av[s] = ap[s * 64];
            f32x4 acc = {bias, bias, bias, bias};
            #pragma unroll
            for (int s = 0; s < 8; ++s)
                acc = __builtin_amdgcn_mfma_f32_16x16x32_bf16(av[s], bw[s], acc, 0, 0, 0);
            #pragma unroll
            for (int i = 0; i < 4; ++i)
                xzsh[t][g][(4 * (l >> 4) + i) * 16 + (l & 15)] = acc[i];
        }
    }
    __syncthreads();

    // ---- step0 (h=c=0) ----
    if (tid < 256) {
        float z0 = xzsh[0][0][tid], z2 = xzsh[0][2][tid], z3 = xzsh[0][3][tid];
        float cn = sigmoidf_(z0) * tanhf(z2);
        float hn = sigmoidf_(z3) * tanhf(cn);
        int tok = token_of(ip[bb * LAT + 0]);
        h_reg = tok != 0 ? hn : 0.0f;
        c_reg = tok != 0 ? cn : 0.0f;
        st_ag_f32(&H[bb * 2048 + myu], h_reg);
        u16 own = to_bf16(h_reg);
        int pair = __shfl_xor((int)own, 1);
        if (!(ul & 1)) {
            u32 val = (u32)own | ((u32)(u16)pair << 16);
            int k0 = myu >> 5, lg = (myu >> 3) & 3, i = myu & 7;
            st_ag_u32((u32*)hA1 + (((k0 * 64) + lg * 16 + bb) * 8 + i) / 2, val);
        }
    }
    gridbar(slots, 0);

    // ---- Steps 1..7 ----
    int g = w >> 2, kq = w & 3;
    int st = bid * 4 + g;
    const bf16x8* bp = (const bf16x8*)(BW + (((size_t)(st * 64) + kq * 16) * 64 + l) * 8);
    const bf16x8* af = (const bf16x8*)hAsh;

    for (int t = 1; t < MAXLEN; ++t) {
        const u16* hAin = (t & 1) ? hA1 : hA0;
        u16* hAout = (t & 1) ? hA0 : hA1;

        // stage hA (64 KB) into LDS: 64 B/thread, pipelined L2-bypass loads
        {
            uint4 r0, r1, r2, r3;
            stage4(hAin + tid * 32, r0, r1, r2, r3);
            uint4* dst = (uint4*)hAsh + tid * 4;
            dst[0] = r0; dst[1] = r1; dst[2] = r2; dst[3] = r3;
        }
        __syncthreads();

        f32x4 acc = {0.f, 0.f, 0.f, 0.f};
        #pragma unroll
        for (int s = 0; s < 16; ++s)
            acc = __builtin_amdgcn_mfma_f32_16x16x32_bf16(
                af[(kq * 16 + s) * 64 + l], bp[s * 64], acc, 0, 0, 0);

        #pragma unroll
        for (int i = 0; i < 4; ++i)
            zsh[w][(4 * (l >> 4) + i) * 16 + (l & 15)] = acc[i];
        __syncthreads();

        if (tid < 256) {
            float z[4];
            #pragma unroll
            for (int gg = 0; gg < 4; ++gg)
                z[gg] = zsh[gg * 4 + 0][tid] + zsh[gg * 4 + 1][tid]
                      + zsh[gg * 4 + 2][tid] + zsh[gg * 4 + 3][tid]
                      + xzsh[t][gg][tid];
            float cn = sigmoidf_(z[1]) * c_reg + sigmoidf_(z[0]) * tanhf(z[2]);
            float hn = sigmoidf_(z[3]) * tanhf(cn);
            int tok = token_of(ip[bb * LAT + t]);
            h_reg = tok != 0 ? hn : h_reg;
            c_reg = tok != 0 ? cn : c_reg;
            st_ag_f32(&H[(t * 16 + bb) * 2048 + myu], h_reg);
            u16 own = to_bf16(h_reg);
            int pair = __shfl_xor((int)own, 1);
            if (!(ul & 1)) {
                u32 val = (u32)own | ((u32)(u16)pair << 16);
                int k0 = myu >> 5, lg = (myu >> 3) & 3, i = myu & 7;
                st_ag_u32((u32*)hAout + (((k0 * 64) + lg * 16 + bb) * 8 + i) / 2, val);
            }
        }
        gridbar(slots, t);
    }

    // ---- Softmax: block bid handles row r = bid (= t*16 + b) ----
    {
        int r = bid;
        int t = r >> 4, b = r & 15;
        const float* hr = H + (size_t)r * VOCAB;
        float v0 = ld_ag_f32(hr + tid);
        float v1 = ld_ag_f32(hr + tid + 1024);
        float m = fmaxf(v0, v1);
        #pragma unroll
        for (int off = 32; off; off >>= 1) m = fmaxf(m, __shfl_down(m, off));
        if (l == 0) redm[w] = m;
        __syncthreads();
        m = redm[0];
        #pragma unroll
        for (int i = 1; i < 16; ++i) m = fmaxf(m, redm[i]);
        float e0 = expf(v0 - m), e1 = expf(v1 - m);
        float s = e0 + e1;
        #pragma unroll
        for (int off = 32; off; off >>= 1) s += __shfl_down(s, off);
        if (l == 0) reds[w] = s;
        __syncthreads();
        s = reds[0];
        #pragma unroll
        for (int i = 1; i < 16; ++i) s += reds[i];
        float* o = out + ((size_t)b * MAXLEN + t) * VOCAB;
        o[tid] = e0 / s;
        o[tid + 1024] = e1 / s;
    }
}

extern "C" void kernel_launch(void* const* d_in, const int* in_sizes, int n_in,
                              void* d_out, int out_size, void* d_ws, size_t ws_size,
                              hipStream_t stream) {
    const float* ip = (const float*)d_in[0];   // (16,16)
    const float* E  = (const float*)d_in[1];   // (2048,256)
    const float* Wk = (const float*)d_in[2];   // (256,8192)
    const float* Wr = (const float*)d_in[3];   // (2048,8192)
    const float* bv = (const float*)d_in[4];   // (8192,)

    char* w = (char*)d_ws;
    float* H   = (float*)w;  w += (size_t)262144 * 4;                  // 1 MB
    u16* XA  = (u16*)w;      w += (size_t)32768 * 2;                   // 64 KB
    u16* hA0 = (u16*)w;      w += (size_t)32768 * 2;
    u16* hA1 = (u16*)w;      w += (size_t)32768 * 2;
    u16* BWk = (u16*)w;      w += (size_t)2097152 * 2;                 // 4 MB
    u16* BW  = (u16*)w;      w += (size_t)16777216 * 2;                // 32 MB
    int* slots = (int*)w;    w += 1024 * 4;                            // 4 KB

    k_pack<<<8192, 256, 0, stream>>>(Wr, BW);
    k_prep<<<1044, 256, 0, stream>>>(Wk, BWk, ip, E, XA, slots);
    k_seq<<<NBLK, 1024, 0, stream>>>(BW, BWk, XA, bv, ip, hA0, hA1,
                                     H, (float*)d_out, slots);
}

// Round 13
// 84.070 us; speedup vs baseline: 1.2046x; 1.2046x over previous
//
#include <hip/hip_runtime.h>
#include <hip/hip_bf16.h>
#include <math.h>

#define VOCAB 2048
#define EMB 256
#define MAXLEN 8
#define NBATCH 16
#define LAT 16

typedef unsigned short u16;
typedef unsigned int u32;
using bf16x8 = __attribute__((ext_vector_type(8))) short;
using f32x4  = __attribute__((ext_vector_type(4))) float;

// token = argmax_j ( j/2048 <= v && v <= (j+1)/2048 ), 0 if none.
// cumsum of uniform softmax is exactly k/2048 in fp32; v*2048 is exact.
__device__ __forceinline__ int token_of(float v) {
    float u = v * 2048.0f;
    if (!(u >= 0.0f) || u > 2048.0f) return 0;   // v<0, v>1, or NaN
    int k = (int)ceilf(u) - 1;
    return k < 0 ? 0 : k;
}

__device__ __forceinline__ float sigmoidf_(float x) { return 1.0f / (1.0f + expf(-x)); }

__device__ __forceinline__ u16 to_bf16(float x) {
    __hip_bfloat16 hb = __float2bfloat16(x);   // RTNE
    return *reinterpret_cast<u16*>(&hb);
}

// ---------------------------------------------------------------------------
// GATE-INTERLEAVED column packing: packed col c = u*4 + g  (u=c>>2, g=c&3).
// Original W column = g*2048 + u. One 16-col MFMA ntile = 4 u's x 4 gates,
// so each block's LSTM update is fully block-local (enables 512 blocks).
// Fragment (l,i) of (nt,k0): bf16( W[(k0*32 + 8*(l>>4) + i)*8192 + gcol ] ),
// gcol = ((l&15)&3)*2048 + nt*4 + ((l&15)>>2). A-frags use the same k-map,
// so any in-fragment k-permutation cancels.
// XCD swizzle: nt = (j&7)*64 + (j>>3) keeps nt-neighbors (which share fp32
// cache lines in step1's scattered read) on the same XCD L2.
// ---------------------------------------------------------------------------

// ---- K1: Wk -> BWk pack (blocks 0..1023) + XA pack (1024..1039) ----
__global__ __launch_bounds__(256) void k_prep(
        const float* __restrict__ Wk, u16* __restrict__ BWk,
        const float* __restrict__ ip, const float* __restrict__ E,
        u16* __restrict__ XA) {
    int bx = blockIdx.x;
    int tid = threadIdx.x;
    if (bx < 1024) {
        int gidx = bx * 256 + tid;      // (nt*8 + k0)*64 + l
        int l = gidx & 63;
        int k0 = (gidx >> 6) & 7;
        int nt = gidx >> 9;
        int n = l & 15;
        int gcol = (n & 3) * 2048 + nt * 4 + (n >> 2);
        const float* s = Wk + (size_t)(k0 * 32 + 8 * (l >> 4)) * 8192 + gcol;
        u16 o[8];
        #pragma unroll
        for (int i = 0; i < 8; ++i) o[i] = to_bf16(s[(size_t)i * 8192]);
        *(uint4*)(BWk + (size_t)gidx * 8) = *(uint4*)o;
    } else {
        int gidx = (bx - 1024) * 256 + tid;   // 0..4095
        int l = gidx & 63;
        int k0 = (gidx >> 6) & 7;
        int t = gidx >> 9;
        int b = l & 15;
        int tok = token_of(ip[b * LAT + t]);
        const float* s = E + (size_t)tok * EMB + k0 * 32 + 8 * (l >> 4);
        u16 o[8];
        #pragma unroll
        for (int i = 0; i < 8; ++i) o[i] = to_bf16(s[i]);
        *(uint4*)(XA + (size_t)gidx * 8) = *(uint4*)o;
    }
}

// ---- K2: xz GEMM for all 8 t (into xz[t][nt][b][n]) + fused step0.
// 512 blocks x 256 thr; wave w handles t = 2w, 2w+1. Block owns ntile nt.
__global__ __launch_bounds__(256) void k_xzmm0(
        const u16* __restrict__ BWk, const u16* __restrict__ XA,
        const float* __restrict__ bv, const float* __restrict__ ip,
        float* __restrict__ xz, float* __restrict__ H,
        float* __restrict__ c, u16* __restrict__ hA1) {
    int j = blockIdx.x;
    int nt = (j & 7) * 64 + (j >> 3);
    int tid = threadIdx.x;
    int w = tid >> 6, l = tid & 63;
    __shared__ float zsh0[256];

    int n = l & 15;
    float bias = bv[(n & 3) * 2048 + nt * 4 + (n >> 2)];

    const bf16x8* bp = (const bf16x8*)(BWk + ((size_t)(nt * 8) * 64 + l) * 8);
    bf16x8 bw[8];
    #pragma unroll
    for (int s = 0; s < 8; ++s) bw[s] = bp[s * 64];

    #pragma unroll
    for (int q = 0; q < 2; ++q) {
        int t = w * 2 + q;
        const bf16x8* ap = (const bf16x8*)(XA + ((size_t)(t * 8) * 64 + l) * 8);
        f32x4 acc = {bias, bias, bias, bias};
        #pragma unroll
        for (int s = 0; s < 8; ++s)
            acc = __builtin_amdgcn_mfma_f32_16x16x32_bf16(ap[s * 64], bw[s], acc, 0, 0, 0);
        #pragma unroll
        for (int i = 0; i < 4; ++i) {
            int b = 4 * (l >> 4) + i;   // D row = batch (m89-verified C/D layout)
            xz[(((size_t)t * 512 + nt) * 16 + b) * 16 + n] = acc[i];
            if (t == 0) zsh0[b * 16 + n] = acc[i];
        }
    }
    __syncthreads();

    // step0 update (h=c=0) for this block's 4 u's x 16 batches
    if (tid < 64) {
        int b = tid >> 2, ul = tid & 3;
        int myu = nt * 4 + ul;
        float z0 = zsh0[b * 16 + ul * 4 + 0];
        float z2 = zsh0[b * 16 + ul * 4 + 2];
        float z3 = zsh0[b * 16 + ul * 4 + 3];
        float cn = sigmoidf_(z0) * tanhf(z2);
        float hn = sigmoidf_(z3) * tanhf(cn);
        int tok = token_of(ip[b * LAT + 0]);
        float hw = tok != 0 ? hn : 0.0f;
        float cw = tok != 0 ? cn : 0.0f;
        c[b * 2048 + myu] = cw;
        H[b * 2048 + myu] = hw;
        u16 own = to_bf16(hw);
        int pair = __shfl_xor((int)own, 1);
        if (!(ul & 1)) {
            u32 val = (u32)own | ((u32)(u16)pair << 16);
            int k0 = myu >> 5, lg = (myu >> 3) & 3, i = myu & 7;
            *((u32*)hA1 + ((((k0 * 64) + lg * 16 + b) * 8 + i) >> 1)) = val;
        }
    }
}

// ---- K3: fused step t. 512 blocks x 256 thr = 4 waves (K-quarters).
// FIRST: read Wr fp32, cvt->bf16 in-register, MFMA AND store BW for t>=2.
// else : read packed BW. Epilogue: block-local gates + masked update.
template<bool FIRST>
__global__ __launch_bounds__(256) void k_step(
        const float* __restrict__ Wr, u16* __restrict__ BW,
        const u16* __restrict__ hAin, u16* __restrict__ hAout,
        const float* __restrict__ xz, const float* __restrict__ ip,
        float* __restrict__ c, float* __restrict__ H, int t) {
    int j = blockIdx.x;
    int nt = (j & 7) * 64 + (j >> 3);
    int tid = threadIdx.x;
    int kq = tid >> 6, l = tid & 63;
    __shared__ float zsh[4][256];

    const bf16x8* ap = (const bf16x8*)(hAin + ((size_t)(kq * 16) * 64 + l) * 8);
    f32x4 acc = {0.f, 0.f, 0.f, 0.f};

    if (FIRST) {
        int n = l & 15;
        int gcol = (n & 3) * 2048 + nt * 4 + (n >> 2);
        const float* wb = Wr + (size_t)(8 * (l >> 4)) * 8192 + gcol;
        float buf[2][8];
        #pragma unroll
        for (int i = 0; i < 8; ++i)
            buf[0][i] = wb[((size_t)(kq * 16) * 32 + i) * 8192];
        #pragma unroll
        for (int i = 0; i < 8; ++i)
            buf[1][i] = wb[((size_t)(kq * 16 + 1) * 32 + i) * 8192];
        #pragma unroll
        for (int s = 0; s < 16; ++s) {
            float nxt[8];
            if (s + 2 < 16) {
                #pragma unroll
                for (int i = 0; i < 8; ++i)
                    nxt[i] = wb[((size_t)(kq * 16 + s + 2) * 32 + i) * 8192];
            }
            u16 o[8];
            #pragma unroll
            for (int i = 0; i < 8; ++i) o[i] = to_bf16(buf[s & 1][i]);
            bf16x8 bfr = *(bf16x8*)o;
            *(uint4*)(BW + (((size_t)(nt * 64) + kq * 16 + s) * 64 + l) * 8) = *(uint4*)o;
            acc = __builtin_amdgcn_mfma_f32_16x16x32_bf16(ap[s * 64], bfr, acc, 0, 0, 0);
            if (s + 2 < 16) {
                #pragma unroll
                for (int i = 0; i < 8; ++i) buf[s & 1][i] = nxt[i];
            }
        }
    } else {
        const bf16x8* bp = (const bf16x8*)(BW + (((size_t)(nt * 64) + kq * 16) * 64 + l) * 8);
        bf16x8 br[8];
        #pragma unroll
        for (int i = 0; i < 8; ++i) br[i] = bp[i * 64];
        #pragma unroll
        for (int s = 0; s < 16; ++s) {
            bf16x8 bb = br[s & 7];
            if (s + 8 < 16) br[s & 7] = bp[(s + 8) * 64];
            acc = __builtin_amdgcn_mfma_f32_16x16x32_bf16(ap[s * 64], bb, acc, 0, 0, 0);
        }
    }

    #pragma unroll
    for (int i = 0; i < 4; ++i)
        zsh[kq][(4 * (l >> 4) + i) * 16 + (l & 15)] = acc[i];
    __syncthreads();

    if (tid < 64) {
        int b = tid >> 2, ul = tid & 3;
        int myu = nt * 4 + ul;
        float4 xv = *(const float4*)&xz[(((size_t)t * 512 + nt) * 16 + b) * 16 + ul * 4];
        float z[4] = {xv.x, xv.y, xv.z, xv.w};
        #pragma unroll
        for (int kk = 0; kk < 4; ++kk) {
            float4 zv = *(const float4*)&zsh[kk][b * 16 + ul * 4];
            z[0] += zv.x; z[1] += zv.y; z[2] += zv.z; z[3] += zv.w;
        }
        int idx = b * 2048 + myu;
        float co = c[idx];
        float ho = H[((size_t)(t - 1) * 16 + b) * 2048 + myu];
        float cn = sigmoidf_(z[1]) * co + sigmoidf_(z[0]) * tanhf(z[2]);
        float hn = sigmoidf_(z[3]) * tanhf(cn);
        int tok = token_of(ip[b * LAT + t]);
        float hw = tok != 0 ? hn : ho;
        float cw = tok != 0 ? cn : co;
        c[idx] = cw;
        H[((size_t)t * 16 + b) * 2048 + myu] = hw;
        u16 own = to_bf16(hw);
        int pair = __shfl_xor((int)own, 1);
        if (!(ul & 1)) {
            u32 val = (u32)own | ((u32)(u16)pair << 16);
            int k0 = myu >> 5, lg = (myu >> 3) & 3, i = myu & 7;
            *((u32*)hAout + ((((k0 * 64) + lg * 16 + b) * 8 + i) >> 1)) = val;
        }
    }
}

// ---- K4: softmax of all 128 recorded h rows -> d_out[b][t][:] ----
__global__ __launch_bounds__(256) void k_softmax(const float* __restrict__ H,
                                                 float* __restrict__ out) {
    int r = blockIdx.x;          // r = t*16 + b
    int t = r >> 4, b = r & 15;
    int tid = threadIdx.x;
    const float* hr = H + (size_t)r * VOCAB;
    float v[8];
    float m = -1e30f;
    #pragma unroll
    for (int i = 0; i < 8; ++i) { v[i] = hr[tid + i * 256]; m = fmaxf(m, v[i]); }

    __shared__ float redm[4], reds[4];
    int wid = tid >> 6, lane = tid & 63;
    #pragma unroll
    for (int off = 32; off; off >>= 1) m = fmaxf(m, __shfl_down(m, off));
    if (lane == 0) redm[wid] = m;
    __syncthreads();
    m = fmaxf(fmaxf(redm[0], redm[1]), fmaxf(redm[2], redm[3]));

    float e[8];
    float s = 0.0f;
    #pragma unroll
    for (int i = 0; i < 8; ++i) { e[i] = expf(v[i] - m); s += e[i]; }
    #pragma unroll
    for (int off = 32; off; off >>= 1) s += __shfl_down(s, off);
    if (lane == 0) reds[wid] = s;
    __syncthreads();
    s = reds[0] + reds[1] + reds[2] + reds[3];

    float* o = out + ((size_t)b * MAXLEN + t) * VOCAB;
    #pragma unroll
    for (int i = 0; i < 8; ++i) o[tid + i * 256] = e[i] / s;
}

extern "C" void kernel_launch(void* const* d_in, const int* in_sizes, int n_in,
                              void* d_out, int out_size, void* d_ws, size_t ws_size,
                              hipStream_t stream) {
    const float* ip = (const float*)d_in[0];   // (16,16)
    const float* E  = (const float*)d_in[1];   // (2048,256)
    const float* Wk = (const float*)d_in[2];   // (256,8192)
    const float* Wr = (const float*)d_in[3];   // (2048,8192)
    const float* bv = (const float*)d_in[4];   // (8192,)

    char* w = (char*)d_ws;
    float* xz  = (float*)w;  w += (size_t)8 * 512 * 16 * 16 * 4;       // 4 MB
    float* H   = (float*)w;  w += (size_t)262144 * 4;                  // 1 MB
    float* c   = (float*)w;  w += (size_t)32768 * 4;                   // 128 KB
    u16* XA  = (u16*)w;      w += (size_t)32768 * 2;                   // 64 KB
    u16* hA0 = (u16*)w;      w += (size_t)32768 * 2;
    u16* hA1 = (u16*)w;      w += (size_t)32768 * 2;
    u16* BWk = (u16*)w;      w += (size_t)2097152 * 2;                 // 4 MB
    u16* BW  = (u16*)w;      w += (size_t)16777216 * 2;                // 32 MB

    k_prep<<<1040, 256, 0, stream>>>(Wk, BWk, ip, E, XA);
    k_xzmm0<<<512, 256, 0, stream>>>(BWk, XA, bv, ip, xz, H, c, hA1);
    u16* hAbuf[2] = {hA0, hA1};
    k_step<true><<<512, 256, 0, stream>>>(Wr, BW, hA1, hA0, xz, ip, c, H, 1);
    for (int t = 2; t < MAXLEN; ++t)
        k_step<false><<<512, 256, 0, stream>>>(Wr, BW, hAbuf[t & 1], hAbuf[(t + 1) & 1],
                                               xz, ip, c, H, t);
    k_softmax<<<128, 256, 0, stream>>>(H, (float*)d_out);
}

// Round 14
// 80.258 us; speedup vs baseline: 1.2618x; 1.0475x over previous
//
#include <hip/hip_runtime.h>
#include <hip/hip_bf16.h>
#include <math.h>

#define VOCAB 2048
#define EMB 256
#define MAXLEN 8
#define NBATCH 16
#define LAT 16

typedef unsigned short u16;
typedef unsigned int u32;
using bf16x8 = __attribute__((ext_vector_type(8))) short;
using f32x4  = __attribute__((ext_vector_type(4))) float;

// token = argmax_j ( j/2048 <= v && v <= (j+1)/2048 ), 0 if none.
// cumsum of uniform softmax is exactly k/2048 in fp32; v*2048 is exact.
__device__ __forceinline__ int token_of(float v) {
    float u = v * 2048.0f;
    if (!(u >= 0.0f) || u > 2048.0f) return 0;   // v<0, v>1, or NaN
    int k = (int)ceilf(u) - 1;
    return k < 0 ? 0 : k;
}

__device__ __forceinline__ float sigmoidf_(float x) { return 1.0f / (1.0f + expf(-x)); }

__device__ __forceinline__ u16 to_bf16(float x) {
    __hip_bfloat16 hb = __float2bfloat16(x);   // RTNE
    return *reinterpret_cast<u16*>(&hb);
}

// ---------------------------------------------------------------------------
// GATE-INTERLEAVED column packing: packed col c = u*4 + g  (u=c>>2, g=c&3).
// One 16-col MFMA ntile = 4 u's x 4 gates -> LSTM update is block-local,
// enabling 512 independent blocks (full chip) in the recurrent step.
// Fragment (l,i) of (nt,k0): bf16( W[(k0*32 + 8*(l>>4) + i)*8192 + gcol ] ),
// gcol = ((l&15)&3)*2048 + nt*4 + ((l&15)>>2). A-frags use the same k-map,
// so any in-fragment k-permutation cancels.
// Pack parallelism note: Wr blocks bx = nt*16 + (k0>>2); adjacent-nt blocks
// are congruent mod 8 -> same XCD -> the 8 nt-chunks of each 128B fp32 line
// are consumed within one XCD's L2 (full line utilization; HBM-bound pack).
// ---------------------------------------------------------------------------

// ---- K1: one-launch pack. [0,8192): Wr->BW; [8192,9216): Wk->BWk;
// [9216,9232): XA = E[token] A-fragments.
__global__ __launch_bounds__(256) void k_pack(
        const float* __restrict__ Wr, const float* __restrict__ Wk,
        const float* __restrict__ ip, const float* __restrict__ E,
        u16* __restrict__ BW, u16* __restrict__ BWk, u16* __restrict__ XA) {
    int bx = blockIdx.x;
    int tid = threadIdx.x;
    if (bx < 8192) {
        int gidx = bx * 256 + tid;      // (nt*64 + k0)*64 + l
        int l = gidx & 63;
        int k0 = (gidx >> 6) & 63;
        int nt = gidx >> 12;
        int n = l & 15;
        int gcol = (n & 3) * 2048 + nt * 4 + (n >> 2);
        const float* s = Wr + (size_t)(k0 * 32 + 8 * (l >> 4)) * 8192 + gcol;
        u16 o[8];
        #pragma unroll
        for (int i = 0; i < 8; ++i) o[i] = to_bf16(s[(size_t)i * 8192]);
        *(uint4*)(BW + (size_t)gidx * 8) = *(uint4*)o;
    } else if (bx < 9216) {
        int gidx = (bx - 8192) * 256 + tid;   // (nt*8 + k0)*64 + l
        int l = gidx & 63;
        int k0 = (gidx >> 6) & 7;
        int nt = gidx >> 9;
        int n = l & 15;
        int gcol = (n & 3) * 2048 + nt * 4 + (n >> 2);
        const float* s = Wk + (size_t)(k0 * 32 + 8 * (l >> 4)) * 8192 + gcol;
        u16 o[8];
        #pragma unroll
        for (int i = 0; i < 8; ++i) o[i] = to_bf16(s[(size_t)i * 8192]);
        *(uint4*)(BWk + (size_t)gidx * 8) = *(uint4*)o;
    } else {
        int gidx = (bx - 9216) * 256 + tid;   // 0..4095
        int l = gidx & 63;
        int k0 = (gidx >> 6) & 7;
        int t = gidx >> 9;
        int b = l & 15;
        int tok = token_of(ip[b * LAT + t]);
        const float* s = E + (size_t)tok * EMB + k0 * 32 + 8 * (l >> 4);
        u16 o[8];
        #pragma unroll
        for (int i = 0; i < 8; ++i) o[i] = to_bf16(s[i]);
        *(uint4*)(XA + (size_t)gidx * 8) = *(uint4*)o;
    }
}

// ---- K2: xz GEMM for all 8 t (into xz[t][nt][b][n]) + fused step0.
// 512 blocks x 256 thr; wave w handles t = 2w, 2w+1. Block owns ntile nt.
__global__ __launch_bounds__(256) void k_xzmm0(
        const u16* __restrict__ BWk, const u16* __restrict__ XA,
        const float* __restrict__ bv, const float* __restrict__ ip,
        float* __restrict__ xz, float* __restrict__ H,
        float* __restrict__ c, u16* __restrict__ hA1) {
    int j = blockIdx.x;
    int nt = (j & 7) * 64 + (j >> 3);
    int tid = threadIdx.x;
    int w = tid >> 6, l = tid & 63;
    __shared__ float zsh0[256];

    int n = l & 15;
    float bias = bv[(n & 3) * 2048 + nt * 4 + (n >> 2)];

    const bf16x8* bp = (const bf16x8*)(BWk + ((size_t)(nt * 8) * 64 + l) * 8);
    bf16x8 bw[8];
    #pragma unroll
    for (int s = 0; s < 8; ++s) bw[s] = bp[s * 64];

    #pragma unroll
    for (int q = 0; q < 2; ++q) {
        int t = w * 2 + q;
        const bf16x8* ap = (const bf16x8*)(XA + ((size_t)(t * 8) * 64 + l) * 8);
        f32x4 acc = {bias, bias, bias, bias};
        #pragma unroll
        for (int s = 0; s < 8; ++s)
            acc = __builtin_amdgcn_mfma_f32_16x16x32_bf16(ap[s * 64], bw[s], acc, 0, 0, 0);
        #pragma unroll
        for (int i = 0; i < 4; ++i) {
            int b = 4 * (l >> 4) + i;   // D row = batch (m89-verified C/D layout)
            xz[(((size_t)t * 512 + nt) * 16 + b) * 16 + n] = acc[i];
            if (t == 0) zsh0[b * 16 + n] = acc[i];
        }
    }
    __syncthreads();

    // step0 update (h=c=0) for this block's 4 u's x 16 batches
    if (tid < 64) {
        int b = tid >> 2, ul = tid & 3;
        int myu = nt * 4 + ul;
        float z0 = zsh0[b * 16 + ul * 4 + 0];
        float z2 = zsh0[b * 16 + ul * 4 + 2];
        float z3 = zsh0[b * 16 + ul * 4 + 3];
        float cn = sigmoidf_(z0) * tanhf(z2);
        float hn = sigmoidf_(z3) * tanhf(cn);
        int tok = token_of(ip[b * LAT + 0]);
        float hw = tok != 0 ? hn : 0.0f;
        float cw = tok != 0 ? cn : 0.0f;
        c[b * 2048 + myu] = cw;
        H[b * 2048 + myu] = hw;
        u16 own = to_bf16(hw);
        int pair = __shfl_xor((int)own, 1);
        if (!(ul & 1)) {
            u32 val = (u32)own | ((u32)(u16)pair << 16);
            int k0 = myu >> 5, lg = (myu >> 3) & 3, i = myu & 7;
            *((u32*)hA1 + ((((k0 * 64) + lg * 16 + b) * 8 + i) >> 1)) = val;
        }
    }
}

// ---- K3: fused step t. 512 blocks x 256 thr = 4 waves (K-quarters).
// Reads packed BW; epilogue: block-local gates + masked update.
__global__ __launch_bounds__(256) void k_step(
        const u16* __restrict__ BW,
        const u16* __restrict__ hAin, u16* __restrict__ hAout,
        const float* __restrict__ xz, const float* __restrict__ ip,
        float* __restrict__ c, float* __restrict__ H, int t) {
    int j = blockIdx.x;
    int nt = (j & 7) * 64 + (j >> 3);
    int tid = threadIdx.x;
    int kq = tid >> 6, l = tid & 63;
    __shared__ float zsh[4][256];

    const bf16x8* ap = (const bf16x8*)(hAin + ((size_t)(kq * 16) * 64 + l) * 8);
    f32x4 acc = {0.f, 0.f, 0.f, 0.f};

    const bf16x8* bp = (const bf16x8*)(BW + (((size_t)(nt * 64) + kq * 16) * 64 + l) * 8);
    bf16x8 br[8];
    #pragma unroll
    for (int i = 0; i < 8; ++i) br[i] = bp[i * 64];
    #pragma unroll
    for (int s = 0; s < 16; ++s) {
        bf16x8 bb = br[s & 7];
        if (s + 8 < 16) br[s & 7] = bp[(s + 8) * 64];
        acc = __builtin_amdgcn_mfma_f32_16x16x32_bf16(ap[s * 64], bb, acc, 0, 0, 0);
    }

    #pragma unroll
    for (int i = 0; i < 4; ++i)
        zsh[kq][(4 * (l >> 4) + i) * 16 + (l & 15)] = acc[i];
    __syncthreads();

    if (tid < 64) {
        int b = tid >> 2, ul = tid & 3;
        int myu = nt * 4 + ul;
        float4 xv = *(const float4*)&xz[(((size_t)t * 512 + nt) * 16 + b) * 16 + ul * 4];
        float z[4] = {xv.x, xv.y, xv.z, xv.w};
        #pragma unroll
        for (int kk = 0; kk < 4; ++kk) {
            float4 zv = *(const float4*)&zsh[kk][b * 16 + ul * 4];
            z[0] += zv.x; z[1] += zv.y; z[2] += zv.z; z[3] += zv.w;
        }
        int idx = b * 2048 + myu;
        float co = c[idx];
        float ho = H[((size_t)(t - 1) * 16 + b) * 2048 + myu];
        float cn = sigmoidf_(z[1]) * co + sigmoidf_(z[0]) * tanhf(z[2]);
        float hn = sigmoidf_(z[3]) * tanhf(cn);
        int tok = token_of(ip[b * LAT + t]);
        float hw = tok != 0 ? hn : ho;
        float cw = tok != 0 ? cn : co;
        c[idx] = cw;
        H[((size_t)t * 16 + b) * 2048 + myu] = hw;
        u16 own = to_bf16(hw);
        int pair = __shfl_xor((int)own, 1);
        if (!(ul & 1)) {
            u32 val = (u32)own | ((u32)(u16)pair << 16);
            int k0 = myu >> 5, lg = (myu >> 3) & 3, i = myu & 7;
            *((u32*)hAout + ((((k0 * 64) + lg * 16 + b) * 8 + i) >> 1)) = val;
        }
    }
}

// ---- K4: softmax of all 128 recorded h rows -> d_out[b][t][:] ----
__global__ __launch_bounds__(256) void k_softmax(const float* __restrict__ H,
                                                 float* __restrict__ out) {
    int r = blockIdx.x;          // r = t*16 + b
    int t = r >> 4, b = r & 15;
    int tid = threadIdx.x;
    const float* hr = H + (size_t)r * VOCAB;
    float v[8];
    float m = -1e30f;
    #pragma unroll
    for (int i = 0; i < 8; ++i) { v[i] = hr[tid + i * 256]; m = fmaxf(m, v[i]); }

    __shared__ float redm[4], reds[4];
    int wid = tid >> 6, lane = tid & 63;
    #pragma unroll
    for (int off = 32; off; off >>= 1) m = fmaxf(m, __shfl_down(m, off));
    if (lane == 0) redm[wid] = m;
    __syncthreads();
    m = fmaxf(fmaxf(redm[0], redm[1]), fmaxf(redm[2], redm[3]));

    float e[8];
    float s = 0.0f;
    #pragma unroll
    for (int i = 0; i < 8; ++i) { e[i] = expf(v[i] - m); s += e[i]; }
    #pragma unroll
    for (int off = 32; off; off >>= 1) s += __shfl_down(s, off);
    if (lane == 0) reds[wid] = s;
    __syncthreads();
    s = reds[0] + reds[1] + reds[2] + reds[3];

    float* o = out + ((size_t)b * MAXLEN + t) * VOCAB;
    #pragma unroll
    for (int i = 0; i < 8; ++i) o[tid + i * 256] = e[i] / s;
}

extern "C" void kernel_launch(void* const* d_in, const int* in_sizes, int n_in,
                              void* d_out, int out_size, void* d_ws, size_t ws_size,
                              hipStream_t stream) {
    const float* ip = (const float*)d_in[0];   // (16,16)
    const float* E  = (const float*)d_in[1];   // (2048,256)
    const float* Wk = (const float*)d_in[2];   // (256,8192)
    const float* Wr = (const float*)d_in[3];   // (2048,8192)
    const float* bv = (const float*)d_in[4];   // (8192,)

    char* w = (char*)d_ws;
    float* xz  = (float*)w;  w += (size_t)8 * 512 * 16 * 16 * 4;       // 4 MB
    float* H   = (float*)w;  w += (size_t)262144 * 4;                  // 1 MB
    float* c   = (float*)w;  w += (size_t)32768 * 4;                   // 128 KB
    u16* XA  = (u16*)w;      w += (size_t)32768 * 2;                   // 64 KB
    u16* hA0 = (u16*)w;      w += (size_t)32768 * 2;
    u16* hA1 = (u16*)w;      w += (size_t)32768 * 2;
    u16* BWk = (u16*)w;      w += (size_t)2097152 * 2;                 // 4 MB
    u16* BW  = (u16*)w;      w += (size_t)16777216 * 2;                // 32 MB

    k_pack<<<9232, 256, 0, stream>>>(Wr, Wk, ip, E, BW, BWk, XA);
    k_xzmm0<<<512, 256, 0, stream>>>(BWk, XA, bv, ip, xz, H, c, hA1);
    u16* hAbuf[2] = {hA0, hA1};
    for (int t = 1; t < MAXLEN; ++t)
        k_step<<<512, 256, 0, stream>>>(BW, hAbuf[t & 1], hAbuf[(t + 1) & 1],
                                        xz, ip, c, H, t);
    k_softmax<<<128, 256, 0, stream>>>(H, (float*)d_out);
}

// Round 15
// 71.453 us; speedup vs baseline: 1.4173x; 1.1232x over previous
//
#include <hip/hip_runtime.h>
#include <hip/hip_bf16.h>
#include <math.h>

#define VOCAB 2048
#define EMB 256
#define MAXLEN 8
#define NBATCH 16
#define LAT 16

typedef unsigned short u16;
typedef unsigned int u32;
using bf16x8 = __attribute__((ext_vector_type(8))) short;
using f32x4  = __attribute__((ext_vector_type(4))) float;

// token = argmax_j ( j/2048 <= v && v <= (j+1)/2048 ), 0 if none.
// cumsum of uniform softmax is exactly k/2048 in fp32; v*2048 is exact.
__device__ __forceinline__ int token_of(float v) {
    float u = v * 2048.0f;
    if (!(u >= 0.0f) || u > 2048.0f) return 0;   // v<0, v>1, or NaN
    int k = (int)ceilf(u) - 1;
    return k < 0 ? 0 : k;
}

__device__ __forceinline__ float sigmoidf_(float x) { return 1.0f / (1.0f + expf(-x)); }

__device__ __forceinline__ u16 to_bf16(float x) {
    __hip_bfloat16 hb = __float2bfloat16(x);   // RTNE
    return *reinterpret_cast<u16*>(&hb);
}

// ---------------------------------------------------------------------------
// GATE-INTERLEAVED column packing: packed col c = u*4 + g  (u=c>>2, g=c&3).
// One 16-col MFMA ntile = 4 u's x 4 gates -> LSTM update is block-local,
// enabling 512 independent blocks (full chip) in the recurrent step.
// Fragment (l,i) of (nt,k0): bf16( W[(k0*32 + 8*(l>>4) + i)*8192 + gcol ] ),
// gcol = ((l&15)&3)*2048 + nt*4 + ((l&15)>>2). A-frags use the same k-map,
// so any in-fragment k-permutation cancels.
// PACK is LDS-transposed: block (kc,uc) reads a 32-row x (4 gates x 128B)
// tile with full-line float4 loads, converts to bf16 into lds[row][c_local]
// (c_local = c - uc*128; the lane mapping is identity in l&15), then writes
// 8 fragments coalesced. Decouples read pattern from fragment layout:
// round-14's direct scatter pack was 12.5% line-utilization, 43 us.
// ---------------------------------------------------------------------------

// ---- K1: one-launch pack. [0,4096): Wr->BW; [4096,4608): Wk->BWk;
// [4608,4624): XA = E[token] A-fragments.
__global__ __launch_bounds__(256) void k_pack(
        const float* __restrict__ Wr, const float* __restrict__ Wk,
        const float* __restrict__ ip, const float* __restrict__ E,
        u16* __restrict__ BW, u16* __restrict__ BWk, u16* __restrict__ XA) {
    __shared__ u16 lds[32][128];     // 8 KB bf16 tile [row_local][packed_col_local]
    int bx = blockIdx.x;
    int tid = threadIdx.x;
    if (bx < 4608) {
        const float* W; u16* dst; int kc, uc, nk0;
        if (bx < 4096) { W = Wr; dst = BW;  kc = bx >> 6;          uc = bx & 63; nk0 = 64; }
        else           { W = Wk; dst = BWk; kc = (bx - 4096) >> 6; uc = (bx - 4096) & 63; nk0 = 8; }

        // read: 4 iters x (8 rows x 4 gates x 8 float4) = 32 rows x 128B/gate
        int row_l = tid >> 5;        // 0..7
        int g  = (tid >> 3) & 3;
        int c4 = tid & 7;
        #pragma unroll
        for (int it = 0; it < 4; ++it) {
            int r = it * 8 + row_l;
            const float4 v = *(const float4*)&W[(size_t)(kc * 32 + r) * 8192
                                                + g * 2048 + uc * 32 + c4 * 4];
            lds[r][c4 * 16 + 0 * 4 + g] = to_bf16(v.x);
            lds[r][c4 * 16 + 1 * 4 + g] = to_bf16(v.y);
            lds[r][c4 * 16 + 2 * 4 + g] = to_bf16(v.z);
            lds[r][c4 * 16 + 3 * 4 + g] = to_bf16(v.w);
        }
        __syncthreads();

        // write: 8 fragments (nt_l 0..7), 2 per thread, 16B coalesced stores
        int w = tid >> 6, l = tid & 63;
        #pragma unroll
        for (int q = 0; q < 2; ++q) {
            int nt_l = q * 4 + w;
            u16 o[8];
            #pragma unroll
            for (int i = 0; i < 8; ++i) o[i] = lds[8 * (l >> 4) + i][nt_l * 16 + (l & 15)];
            int nt = uc * 8 + nt_l;
            *(uint4*)(dst + ((size_t)(nt * nk0 + kc) * 64 + l) * 8) = *(uint4*)o;
        }
    } else {
        int gidx = (bx - 4608) * 256 + tid;   // 0..4095
        int l = gidx & 63;
        int k0 = (gidx >> 6) & 7;
        int t = gidx >> 9;
        int b = l & 15;
        int tok = token_of(ip[b * LAT + t]);
        const float* s = E + (size_t)tok * EMB + k0 * 32 + 8 * (l >> 4);
        u16 o[8];
        #pragma unroll
        for (int i = 0; i < 8; ++i) o[i] = to_bf16(s[i]);
        *(uint4*)(XA + (size_t)gidx * 8) = *(uint4*)o;
    }
}

// ---- K2: xz GEMM for all 8 t (into xz[t][nt][b][n]) + fused step0.
// 512 blocks x 256 thr; wave w handles t = 2w, 2w+1. Block owns ntile nt.
__global__ __launch_bounds__(256) void k_xzmm0(
        const u16* __restrict__ BWk, const u16* __restrict__ XA,
        const float* __restrict__ bv, const float* __restrict__ ip,
        float* __restrict__ xz, float* __restrict__ H,
        float* __restrict__ c, u16* __restrict__ hA1) {
    int j = blockIdx.x;
    int nt = (j & 7) * 64 + (j >> 3);
    int tid = threadIdx.x;
    int w = tid >> 6, l = tid & 63;
    __shared__ float zsh0[256];

    int n = l & 15;
    float bias = bv[(n & 3) * 2048 + nt * 4 + (n >> 2)];

    const bf16x8* bp = (const bf16x8*)(BWk + ((size_t)(nt * 8) * 64 + l) * 8);
    bf16x8 bw[8];
    #pragma unroll
    for (int s = 0; s < 8; ++s) bw[s] = bp[s * 64];

    #pragma unroll
    for (int q = 0; q < 2; ++q) {
        int t = w * 2 + q;
        const bf16x8* ap = (const bf16x8*)(XA + ((size_t)(t * 8) * 64 + l) * 8);
        f32x4 acc = {bias, bias, bias, bias};
        #pragma unroll
        for (int s = 0; s < 8; ++s)
            acc = __builtin_amdgcn_mfma_f32_16x16x32_bf16(ap[s * 64], bw[s], acc, 0, 0, 0);
        #pragma unroll
        for (int i = 0; i < 4; ++i) {
            int b = 4 * (l >> 4) + i;   // D row = batch (m89-verified C/D layout)
            xz[(((size_t)t * 512 + nt) * 16 + b) * 16 + n] = acc[i];
            if (t == 0) zsh0[b * 16 + n] = acc[i];
        }
    }
    __syncthreads();

    // step0 update (h=c=0) for this block's 4 u's x 16 batches
    if (tid < 64) {
        int b = tid >> 2, ul = tid & 3;
        int myu = nt * 4 + ul;
        float z0 = zsh0[b * 16 + ul * 4 + 0];
        float z2 = zsh0[b * 16 + ul * 4 + 2];
        float z3 = zsh0[b * 16 + ul * 4 + 3];
        float cn = sigmoidf_(z0) * tanhf(z2);
        float hn = sigmoidf_(z3) * tanhf(cn);
        int tok = token_of(ip[b * LAT + 0]);
        float hw = tok != 0 ? hn : 0.0f;
        float cw = tok != 0 ? cn : 0.0f;
        c[b * 2048 + myu] = cw;
        H[b * 2048 + myu] = hw;
        u16 own = to_bf16(hw);
        int pair = __shfl_xor((int)own, 1);
        if (!(ul & 1)) {
            u32 val = (u32)own | ((u32)(u16)pair << 16);
            int k0 = myu >> 5, lg = (myu >> 3) & 3, i = myu & 7;
            *((u32*)hA1 + ((((k0 * 64) + lg * 16 + b) * 8 + i) >> 1)) = val;
        }
    }
}

// ---- K3: fused step t. 512 blocks x 256 thr = 4 waves (K-quarters).
// Reads packed BW; epilogue: block-local gates + masked update.
__global__ __launch_bounds__(256) void k_step(
        const u16* __restrict__ BW,
        const u16* __restrict__ hAin, u16* __restrict__ hAout,
        const float* __restrict__ xz, const float* __restrict__ ip,
        float* __restrict__ c, float* __restrict__ H, int t) {
    int j = blockIdx.x;
    int nt = (j & 7) * 64 + (j >> 3);
    int tid = threadIdx.x;
    int kq = tid >> 6, l = tid & 63;
    __shared__ float zsh[4][256];

    const bf16x8* ap = (const bf16x8*)(hAin + ((size_t)(kq * 16) * 64 + l) * 8);
    f32x4 acc = {0.f, 0.f, 0.f, 0.f};

    const bf16x8* bp = (const bf16x8*)(BW + (((size_t)(nt * 64) + kq * 16) * 64 + l) * 8);
    bf16x8 br[8];
    #pragma unroll
    for (int i = 0; i < 8; ++i) br[i] = bp[i * 64];
    #pragma unroll
    for (int s = 0; s < 16; ++s) {
        bf16x8 bb = br[s & 7];
        if (s + 8 < 16) br[s & 7] = bp[(s + 8) * 64];
        acc = __builtin_amdgcn_mfma_f32_16x16x32_bf16(ap[s * 64], bb, acc, 0, 0, 0);
    }

    #pragma unroll
    for (int i = 0; i < 4; ++i)
        zsh[kq][(4 * (l >> 4) + i) * 16 + (l & 15)] = acc[i];
    __syncthreads();

    if (tid < 64) {
        int b = tid >> 2, ul = tid & 3;
        int myu = nt * 4 + ul;
        float4 xv = *(const float4*)&xz[(((size_t)t * 512 + nt) * 16 + b) * 16 + ul * 4];
        float z[4] = {xv.x, xv.y, xv.z, xv.w};
        #pragma unroll
        for (int kk = 0; kk < 4; ++kk) {
            float4 zv = *(const float4*)&zsh[kk][b * 16 + ul * 4];
            z[0] += zv.x; z[1] += zv.y; z[2] += zv.z; z[3] += zv.w;
        }
        int idx = b * 2048 + myu;
        float co = c[idx];
        float ho = H[((size_t)(t - 1) * 16 + b) * 2048 + myu];
        float cn = sigmoidf_(z[1]) * co + sigmoidf_(z[0]) * tanhf(z[2]);
        float hn = sigmoidf_(z[3]) * tanhf(cn);
        int tok = token_of(ip[b * LAT + t]);
        float hw = tok != 0 ? hn : ho;
        float cw = tok != 0 ? cn : co;
        c[idx] = cw;
        H[((size_t)t * 16 + b) * 2048 + myu] = hw;
        u16 own = to_bf16(hw);
        int pair = __shfl_xor((int)own, 1);
        if (!(ul & 1)) {
            u32 val = (u32)own | ((u32)(u16)pair << 16);
            int k0 = myu >> 5, lg = (myu >> 3) & 3, i = myu & 7;
            *((u32*)hAout + ((((k0 * 64) + lg * 16 + b) * 8 + i) >> 1)) = val;
        }
    }
}

// ---- K4: softmax of all 128 recorded h rows -> d_out[b][t][:] ----
__global__ __launch_bounds__(256) void k_softmax(const float* __restrict__ H,
                                                 float* __restrict__ out) {
    int r = blockIdx.x;          // r = t*16 + b
    int t = r >> 4, b = r & 15;
    int tid = threadIdx.x;
    const float* hr = H + (size_t)r * VOCAB;
    float v[8];
    float m = -1e30f;
    #pragma unroll
    for (int i = 0; i < 8; ++i) { v[i] = hr[tid + i * 256]; m = fmaxf(m, v[i]); }

    __shared__ float redm[4], reds[4];
    int wid = tid >> 6, lane = tid & 63;
    #pragma unroll
    for (int off = 32; off; off >>= 1) m = fmaxf(m, __shfl_down(m, off));
    if (lane == 0) redm[wid] = m;
    __syncthreads();
    m = fmaxf(fmaxf(redm[0], redm[1]), fmaxf(redm[2], redm[3]));

    float e[8];
    float s = 0.0f;
    #pragma unroll
    for (int i = 0; i < 8; ++i) { e[i] = expf(v[i] - m); s += e[i]; }
    #pragma unroll
    for (int off = 32; off; off >>= 1) s += __shfl_down(s, off);
    if (lane == 0) reds[wid] = s;
    __syncthreads();
    s = reds[0] + reds[1] + reds[2] + reds[3];

    float* o = out + ((size_t)b * MAXLEN + t) * VOCAB;
    #pragma unroll
    for (int i = 0; i < 8; ++i) o[tid + i * 256] = e[i] / s;
}

extern "C" void kernel_launch(void* const* d_in, const int* in_sizes, int n_in,
                              void* d_out, int out_size, void* d_ws, size_t ws_size,
                              hipStream_t stream) {
    const float* ip = (const float*)d_in[0];   // (16,16)
    const float* E  = (const float*)d_in[1];   // (2048,256)
    const float* Wk = (const float*)d_in[2];   // (256,8192)
    const float* Wr = (const float*)d_in[3];   // (2048,8192)
    const float* bv = (const float*)d_in[4];   // (8192,)

    char* w = (char*)d_ws;
    float* xz  = (float*)w;  w += (size_t)8 * 512 * 16 * 16 * 4;       // 4 MB
    float* H   = (float*)w;  w += (size_t)262144 * 4;                  // 1 MB
    float* c   = (float*)w;  w += (size_t)32768 * 4;                   // 128 KB
    u16* XA  = (u16*)w;      w += (size_t)32768 * 2;                   // 64 KB
    u16* hA0 = (u16*)w;      w += (size_t)32768 * 2;
    u16* hA1 = (u16*)w;      w += (size_t)32768 * 2;
    u16* BWk = (u16*)w;      w += (size_t)2097152 * 2;                 // 4 MB
    u16* BW  = (u16*)w;      w += (size_t)16777216 * 2;                // 32 MB

    k_pack<<<4624, 256, 0, stream>>>(Wr, Wk, ip, E, BW, BWk, XA);
    k_xzmm0<<<512, 256, 0, stream>>>(BWk, XA, bv, ip, xz, H, c, hA1);
    u16* hAbuf[2] = {hA0, hA1};
    for (int t = 1; t < MAXLEN; ++t)
        k_step<<<512, 256, 0, stream>>>(BW, hAbuf[t & 1], hAbuf[(t + 1) & 1],
                                        xz, ip, c, H, t);
    k_softmax<<<128, 256, 0, stream>>>(H, (float*)d_out);
}

// Round 16
// 69.937 us; speedup vs baseline: 1.4480x; 1.0217x over previous
//
#include <hip/hip_runtime.h>
#include <hip/hip_bf16.h>
#include <math.h>

#define VOCAB 2048
#define EMB 256
#define MAXLEN 8
#define NBATCH 16
#define LAT 16

typedef unsigned short u16;
typedef unsigned int u32;
using bf16x8 = __attribute__((ext_vector_type(8))) short;
using f32x4  = __attribute__((ext_vector_type(4))) float;

// token = argmax_j ( j/2048 <= v && v <= (j+1)/2048 ), 0 if none.
// cumsum of uniform softmax is exactly k/2048 in fp32; v*2048 is exact.
__device__ __forceinline__ int token_of(float v) {
    float u = v * 2048.0f;
    if (!(u >= 0.0f) || u > 2048.0f) return 0;   // v<0, v>1, or NaN
    int k = (int)ceilf(u) - 1;
    return k < 0 ? 0 : k;
}

__device__ __forceinline__ float sigmoidf_(float x) { return 1.0f / (1.0f + expf(-x)); }

__device__ __forceinline__ u16 to_bf16(float x) {
    __hip_bfloat16 hb = __float2bfloat16(x);   // RTNE
    return *reinterpret_cast<u16*>(&hb);
}

// ---------------------------------------------------------------------------
// GATE-INTERLEAVED column packing: packed col c = u*4 + g  (u=c>>2, g=c&3).
// One 16-col MFMA ntile = 4 u's x 4 gates -> LSTM update is block-local,
// enabling 512 independent blocks (full chip) in the recurrent step.
// Fragment (l,i) of (nt,k0): bf16( W[(k0*32 + 8*(l>>4) + i)*8192 + gcol ] ),
// gcol = ((l&15)&3)*2048 + nt*4 + ((l&15)>>2). A-frags use the same k-map,
// so any in-fragment k-permutation cancels.
// PACK (LDS-transposed, vector writes): thread (r, grp) reads float2 from
// each gate region at u0 = uc*32 + grp*2 (4 x 8B coalesced loads), assembles
// packed cols grp*8..grp*8+7 = {g0.x,g1.x,g2.x,g3.x,g0.y,g1.y,g2.y,g3.y},
// writes ONE ds_write_b128. (Round-15's 64 scalar b16 writes/thread was the
// pack bottleneck: 34 us vs the ~20 us HBM floor.)
// ---------------------------------------------------------------------------

// ---- K1: one-launch pack. [0,4096): Wr->BW; [4096,4608): Wk->BWk;
// [4608,4624): XA = E[token] A-fragments.
__global__ __launch_bounds__(256) void k_pack(
        const float* __restrict__ Wr, const float* __restrict__ Wk,
        const float* __restrict__ ip, const float* __restrict__ E,
        u16* __restrict__ BW, u16* __restrict__ BWk, u16* __restrict__ XA) {
    __shared__ __align__(16) u16 lds[32][128];   // 8 KB [row][packed_col_local]
    int bx = blockIdx.x;
    int tid = threadIdx.x;
    if (bx < 4608) {
        const float* W; u16* dst; int kc, uc, nk0;
        if (bx < 4096) { W = Wr; dst = BW;  kc = bx >> 6;          uc = bx & 63; nk0 = 64; }
        else           { W = Wk; dst = BWk; kc = (bx - 4096) >> 6; uc = (bx - 4096) & 63; nk0 = 8; }

        // fill: 2 iters; thread -> (row r, 8-col group grp); 4x float2 + 1x b128
        #pragma unroll
        for (int it = 0; it < 2; ++it) {
            int lin = it * 256 + tid;        // 0..511
            int r = lin >> 4;                // 0..31
            int grp = lin & 15;              // 0..15
            const float* base = W + (size_t)(kc * 32 + r) * 8192 + uc * 32 + grp * 2;
            float2 v0 = *(const float2*)(base + 0 * 2048);
            float2 v1 = *(const float2*)(base + 1 * 2048);
            float2 v2 = *(const float2*)(base + 2 * 2048);
            float2 v3 = *(const float2*)(base + 3 * 2048);
            u16 o[8] = {to_bf16(v0.x), to_bf16(v1.x), to_bf16(v2.x), to_bf16(v3.x),
                        to_bf16(v0.y), to_bf16(v1.y), to_bf16(v2.y), to_bf16(v3.y)};
            *(uint4*)&lds[r][grp * 8] = *(uint4*)o;
        }
        __syncthreads();

        // assemble: 8 fragments (nt_l 0..7), 2 per thread, 16B coalesced stores
        int w = tid >> 6, l = tid & 63;
        #pragma unroll
        for (int q = 0; q < 2; ++q) {
            int nt_l = q * 4 + w;
            u16 o[8];
            #pragma unroll
            for (int i = 0; i < 8; ++i) o[i] = lds[8 * (l >> 4) + i][nt_l * 16 + (l & 15)];
            int nt = uc * 8 + nt_l;
            *(uint4*)(dst + ((size_t)(nt * nk0 + kc) * 64 + l) * 8) = *(uint4*)o;
        }
    } else {
        int gidx = (bx - 4608) * 256 + tid;   // 0..4095
        int l = gidx & 63;
        int k0 = (gidx >> 6) & 7;
        int t = gidx >> 9;
        int b = l & 15;
        int tok = token_of(ip[b * LAT + t]);
        const float* s = E + (size_t)tok * EMB + k0 * 32 + 8 * (l >> 4);
        u16 o[8];
        #pragma unroll
        for (int i = 0; i < 8; ++i) o[i] = to_bf16(s[i]);
        *(uint4*)(XA + (size_t)gidx * 8) = *(uint4*)o;
    }
}

// ---- K2: xz GEMM for all 8 t (into xz[t][nt][b][n]) + fused step0.
// 512 blocks x 256 thr; wave w handles t = 2w, 2w+1. Block owns ntile nt.
__global__ __launch_bounds__(256) void k_xzmm0(
        const u16* __restrict__ BWk, const u16* __restrict__ XA,
        const float* __restrict__ bv, const float* __restrict__ ip,
        float* __restrict__ xz, float* __restrict__ H,
        float* __restrict__ c, u16* __restrict__ hA1) {
    int j = blockIdx.x;
    int nt = (j & 7) * 64 + (j >> 3);
    int tid = threadIdx.x;
    int w = tid >> 6, l = tid & 63;
    __shared__ float zsh0[256];

    int n = l & 15;
    float bias = bv[(n & 3) * 2048 + nt * 4 + (n >> 2)];

    const bf16x8* bp = (const bf16x8*)(BWk + ((size_t)(nt * 8) * 64 + l) * 8);
    bf16x8 bw[8];
    #pragma unroll
    for (int s = 0; s < 8; ++s) bw[s] = bp[s * 64];

    #pragma unroll
    for (int q = 0; q < 2; ++q) {
        int t = w * 2 + q;
        const bf16x8* ap = (const bf16x8*)(XA + ((size_t)(t * 8) * 64 + l) * 8);
        f32x4 acc = {bias, bias, bias, bias};
        #pragma unroll
        for (int s = 0; s < 8; ++s)
            acc = __builtin_amdgcn_mfma_f32_16x16x32_bf16(ap[s * 64], bw[s], acc, 0, 0, 0);
        #pragma unroll
        for (int i = 0; i < 4; ++i) {
            int b = 4 * (l >> 4) + i;   // D row = batch (m89-verified C/D layout)
            xz[(((size_t)t * 512 + nt) * 16 + b) * 16 + n] = acc[i];
            if (t == 0) zsh0[b * 16 + n] = acc[i];
        }
    }
    __syncthreads();

    // step0 update (h=c=0) for this block's 4 u's x 16 batches
    if (tid < 64) {
        int b = tid >> 2, ul = tid & 3;
        int myu = nt * 4 + ul;
        float z0 = zsh0[b * 16 + ul * 4 + 0];
        float z2 = zsh0[b * 16 + ul * 4 + 2];
        float z3 = zsh0[b * 16 + ul * 4 + 3];
        float cn = sigmoidf_(z0) * tanhf(z2);
        float hn = sigmoidf_(z3) * tanhf(cn);
        int tok = token_of(ip[b * LAT + 0]);
        float hw = tok != 0 ? hn : 0.0f;
        float cw = tok != 0 ? cn : 0.0f;
        c[b * 2048 + myu] = cw;
        H[b * 2048 + myu] = hw;
        u16 own = to_bf16(hw);
        int pair = __shfl_xor((int)own, 1);
        if (!(ul & 1)) {
            u32 val = (u32)own | ((u32)(u16)pair << 16);
            int k0 = myu >> 5, lg = (myu >> 3) & 3, i = myu & 7;
            *((u32*)hA1 + ((((k0 * 64) + lg * 16 + b) * 8 + i) >> 1)) = val;
        }
    }
}

// ---- K3: fused step t. 512 blocks x 512 thr = 8 waves (K-eighths).
// 4 waves/SIMD occupancy; 16 loads in flight per wave before the MFMA chain.
__global__ __launch_bounds__(512) void k_step(
        const u16* __restrict__ BW,
        const u16* __restrict__ hAin, u16* __restrict__ hAout,
        const float* __restrict__ xz, const float* __restrict__ ip,
        float* __restrict__ c, float* __restrict__ H, int t) {
    int j = blockIdx.x;
    int nt = (j & 7) * 64 + (j >> 3);
    int tid = threadIdx.x;
    int kq = tid >> 6, l = tid & 63;     // kq = K-eighth (0..7)
    __shared__ float zsh[8][256];

    const bf16x8* ap = (const bf16x8*)(hAin + ((size_t)(kq * 8) * 64 + l) * 8);
    const bf16x8* bp = (const bf16x8*)(BW + (((size_t)(nt * 64) + kq * 8) * 64 + l) * 8);
    bf16x8 ar[8], br[8];
    #pragma unroll
    for (int i = 0; i < 8; ++i) { ar[i] = ap[i * 64]; br[i] = bp[i * 64]; }

    f32x4 acc = {0.f, 0.f, 0.f, 0.f};
    #pragma unroll
    for (int s = 0; s < 8; ++s)
        acc = __builtin_amdgcn_mfma_f32_16x16x32_bf16(ar[s], br[s], acc, 0, 0, 0);

    #pragma unroll
    for (int i = 0; i < 4; ++i)
        zsh[kq][(4 * (l >> 4) + i) * 16 + (l & 15)] = acc[i];
    __syncthreads();

    if (tid < 64) {
        int b = tid >> 2, ul = tid & 3;
        int myu = nt * 4 + ul;
        float4 xv = *(const float4*)&xz[(((size_t)t * 512 + nt) * 16 + b) * 16 + ul * 4];
        float z[4] = {xv.x, xv.y, xv.z, xv.w};
        #pragma unroll
        for (int kk = 0; kk < 8; ++kk) {
            float4 zv = *(const float4*)&zsh[kk][b * 16 + ul * 4];
            z[0] += zv.x; z[1] += zv.y; z[2] += zv.z; z[3] += zv.w;
        }
        int idx = b * 2048 + myu;
        float co = c[idx];
        float ho = H[((size_t)(t - 1) * 16 + b) * 2048 + myu];
        float cn = sigmoidf_(z[1]) * co + sigmoidf_(z[0]) * tanhf(z[2]);
        float hn = sigmoidf_(z[3]) * tanhf(cn);
        int tok = token_of(ip[b * LAT + t]);
        float hw = tok != 0 ? hn : ho;
        float cw = tok != 0 ? cn : co;
        c[idx] = cw;
        H[((size_t)t * 16 + b) * 2048 + myu] = hw;
        u16 own = to_bf16(hw);
        int pair = __shfl_xor((int)own, 1);
        if (!(ul & 1)) {
            u32 val = (u32)own | ((u32)(u16)pair << 16);
            int k0 = myu >> 5, lg = (myu >> 3) & 3, i = myu & 7;
            *((u32*)hAout + ((((k0 * 64) + lg * 16 + b) * 8 + i) >> 1)) = val;
        }
    }
}

// ---- K4: softmax of all 128 recorded h rows -> d_out[b][t][:] ----
__global__ __launch_bounds__(256) void k_softmax(const float* __restrict__ H,
                                                 float* __restrict__ out) {
    int r = blockIdx.x;          // r = t*16 + b
    int t = r >> 4, b = r & 15;
    int tid = threadIdx.x;
    const float* hr = H + (size_t)r * VOCAB;
    float v[8];
    float m = -1e30f;
    #pragma unroll
    for (int i = 0; i < 8; ++i) { v[i] = hr[tid + i * 256]; m = fmaxf(m, v[i]); }

    __shared__ float redm[4], reds[4];
    int wid = tid >> 6, lane = tid & 63;
    #pragma unroll
    for (int off = 32; off; off >>= 1) m = fmaxf(m, __shfl_down(m, off));
    if (lane == 0) redm[wid] = m;
    __syncthreads();
    m = fmaxf(fmaxf(redm[0], redm[1]), fmaxf(redm[2], redm[3]));

    float e[8];
    float s = 0.0f;
    #pragma unroll
    for (int i = 0; i < 8; ++i) { e[i] = expf(v[i] - m); s += e[i]; }
    #pragma unroll
    for (int off = 32; off; off >>= 1) s += __shfl_down(s, off);
    if (lane == 0) reds[wid] = s;
    __syncthreads();
    s = reds[0] + reds[1] + reds[2] + reds[3];

    float* o = out + ((size_t)b * MAXLEN + t) * VOCAB;
    #pragma unroll
    for (int i = 0; i < 8; ++i) o[tid + i * 256] = e[i] / s;
}

extern "C" void kernel_launch(void* const* d_in, const int* in_sizes, int n_in,
                              void* d_out, int out_size, void* d_ws, size_t ws_size,
                              hipStream_t stream) {
    const float* ip = (const float*)d_in[0];   // (16,16)
    const float* E  = (const float*)d_in[1];   // (2048,256)
    const float* Wk = (const float*)d_in[2];   // (256,8192)
    const float* Wr = (const float*)d_in[3];   // (2048,8192)
    const float* bv = (const float*)d_in[4];   // (8192,)

    char* w = (char*)d_ws;
    float* xz  = (float*)w;  w += (size_t)8 * 512 * 16 * 16 * 4;       // 4 MB
    float* H   = (float*)w;  w += (size_t)262144 * 4;                  // 1 MB
    float* c   = (float*)w;  w += (size_t)32768 * 4;                   // 128 KB
    u16* XA  = (u16*)w;      w += (size_t)32768 * 2;                   // 64 KB
    u16* hA0 = (u16*)w;      w += (size_t)32768 * 2;
    u16* hA1 = (u16*)w;      w += (size_t)32768 * 2;
    u16* BWk = (u16*)w;      w += (size_t)2097152 * 2;                 // 4 MB
    u16* BW  = (u16*)w;      w += (size_t)16777216 * 2;                // 32 MB

    k_pack<<<4624, 256, 0, stream>>>(Wr, Wk, ip, E, BW, BWk, XA);
    k_xzmm0<<<512, 256, 0, stream>>>(BWk, XA, bv, ip, xz, H, c, hA1);
    u16* hAbuf[2] = {hA0, hA1};
    for (int t = 1; t < MAXLEN; ++t)
        k_step<<<512, 512, 0, stream>>>(BW, hAbuf[t & 1], hAbuf[(t + 1) & 1],
                                        xz, ip, c, H, t);
    k_softmax<<<128, 256, 0, stream>>>(H, (float*)d_out);
}